// Round 1
// baseline (3981.723 us; speedup 1.0000x reference)
//
#include <hip/hip_runtime.h>
#include <math.h>

#define N_NODES 50000
#define N_EDGES 800000
#define HID 256
#define OUT_C 128
#define NEG_SLOPE 0.2f

// v[k] = sum_j W[k][j] * att[j]   (W is [cin][cout] row-major, att is [cout])
__global__ __launch_bounds__(64) void compute_v_kernel(
    const float* __restrict__ W, const float* __restrict__ att,
    float* __restrict__ v, int cout) {
    int k = blockIdx.x;
    int lane = threadIdx.x;  // 64 threads = 1 wave
    float sum = 0.f;
    for (int j = lane; j < cout; j += 64)
        sum += W[k * cout + j] * att[j];
    #pragma unroll
    for (int off = 32; off > 0; off >>= 1)
        sum += __shfl_down(sum, off);
    if (lane == 0) v[k] = sum;
}

// a_src[n] = x[n,:] . vsrc ; a_dst[n] = x[n,:] . vdst   (one wave per node)
__global__ __launch_bounds__(256) void compute_a_kernel(
    const float* __restrict__ x, const float* __restrict__ vsrc,
    const float* __restrict__ vdst, float* __restrict__ a_src,
    float* __restrict__ a_dst, int n, int c) {
    int wave = (int)((blockIdx.x * (unsigned)blockDim.x + threadIdx.x) >> 6);
    int lane = threadIdx.x & 63;
    if (wave >= n) return;
    const float* xr = x + (size_t)wave * c;
    float ss = 0.f, sd = 0.f;
    for (int j = lane; j < c; j += 64) {
        float xv = xr[j];
        ss += xv * vsrc[j];
        sd += xv * vdst[j];
    }
    #pragma unroll
    for (int off = 32; off > 0; off >>= 1) {
        ss += __shfl_down(ss, off);
        sd += __shfl_down(sd, off);
    }
    if (lane == 0) { a_src[wave] = ss; a_dst[wave] = sd; }
}

// H[n, :] = A[n, :] @ W   (A: [n][CIN], W: [CIN][COUT]); block = COUT threads, TM rows/block
template <int CIN, int COUT, int TM>
__global__ __launch_bounds__(COUT) void gemm_kernel(
    const float* __restrict__ A, const float* __restrict__ W,
    float* __restrict__ H, int n) {
    __shared__ __align__(16) float xs[TM][CIN];
    int row0 = blockIdx.x * TM;
    int tid = threadIdx.x;
    // stage A tile into LDS with float4 loads
    const int total4 = TM * CIN / 4;
    float4* xs4 = (float4*)&xs[0][0];
    for (int i = tid; i < total4; i += COUT) {
        int elem = i * 4;
        int r = elem / CIN;
        int gr = row0 + r;
        float4 val = make_float4(0.f, 0.f, 0.f, 0.f);
        if (gr < n) val = *(const float4*)(A + (size_t)gr * CIN + (elem & (CIN - 1)));
        xs4[i] = val;
    }
    __syncthreads();
    float acc[TM];
    #pragma unroll
    for (int r = 0; r < TM; r++) acc[r] = 0.f;
    #pragma unroll 4
    for (int k = 0; k < CIN; k++) {
        float w = W[k * COUT + tid];   // coalesced across threads; L2-resident
        #pragma unroll
        for (int r = 0; r < TM; r++)
            acc[r] += xs[r][k] * w;    // LDS broadcast (same addr all lanes)
    }
    #pragma unroll
    for (int r = 0; r < TM; r++) {
        int gr = row0 + r;
        if (gr < n) H[(size_t)gr * COUT + tid] = acc[r];
    }
}

// out[i] = bias[i & (C-1)]
template <int C>
__global__ __launch_bounds__(256) void init_bias_kernel(
    float* __restrict__ out, const float* __restrict__ bias, int total) {
    int i = blockIdx.x * 256 + threadIdx.x;
    if (i < total) out[i] = bias[i & (C - 1)];
}

__global__ __launch_bounds__(256) void relu_kernel(float* __restrict__ x, int total) {
    int i = blockIdx.x * 256 + threadIdx.x;
    if (i < total) x[i] = fmaxf(x[i], 0.f);
}

// ex[e] = exp(lrelu(a_src[src[e]] + a_dst[dst[e]])); s[dst[e]] += ex[e]
__global__ __launch_bounds__(256) void edge_softmax_kernel(
    const int* __restrict__ src, const int* __restrict__ dst,
    const float* __restrict__ a_src, const float* __restrict__ a_dst,
    float* __restrict__ ex, float* __restrict__ s) {
    int e = blockIdx.x * 256 + threadIdx.x;
    if (e >= N_EDGES) return;
    float logit = a_src[src[e]] + a_dst[dst[e]];
    if (logit < 0.f) logit *= NEG_SLOPE;
    float v = expf(logit);   // softmax shift-invariant; logits O(1..10), no overflow
    ex[e] = v;
    atomicAdd(&s[dst[e]], v);
}

// one wave per edge: out[dst[e], :] += (ex[e]/(s[dst[e]]+eps)) * h[src[e], :]
template <int C>
__global__ __launch_bounds__(256) void edge_aggregate_kernel(
    const int* __restrict__ src, const int* __restrict__ dst,
    const float* __restrict__ ex, const float* __restrict__ s,
    const float* __restrict__ h, float* __restrict__ out) {
    int wave = (int)((blockIdx.x * 256u + threadIdx.x) >> 6);
    int lane = threadIdx.x & 63;
    if (wave >= N_EDGES) return;
    int d = dst[wave];
    float alpha = ex[wave] / (s[d] + 1e-16f);
    const float* hr = h + (size_t)src[wave] * C;
    float* orow = out + (size_t)d * C;
    if (C == 256) {
        float4 hv = *(const float4*)(hr + lane * 4);
        atomicAdd(&orow[lane * 4 + 0], alpha * hv.x);
        atomicAdd(&orow[lane * 4 + 1], alpha * hv.y);
        atomicAdd(&orow[lane * 4 + 2], alpha * hv.z);
        atomicAdd(&orow[lane * 4 + 3], alpha * hv.w);
    } else {
        float2 hv = *(const float2*)(hr + lane * 2);
        atomicAdd(&orow[lane * 2 + 0], alpha * hv.x);
        atomicAdd(&orow[lane * 2 + 1], alpha * hv.y);
    }
}

extern "C" void kernel_launch(void* const* d_in, const int* in_sizes, int n_in,
                              void* d_out, int out_size, void* d_ws, size_t ws_size,
                              hipStream_t stream) {
    const float* x     = (const float*)d_in[0];
    const int*   edge  = (const int*)d_in[1];
    const int*   src   = edge;
    const int*   dst   = edge + N_EDGES;
    const float* W1s   = (const float*)d_in[2];
    const float* W1d   = (const float*)d_in[3];
    const float* att1s = (const float*)d_in[4];
    const float* att1d = (const float*)d_in[5];
    const float* b1    = (const float*)d_in[6];
    const float* W2s   = (const float*)d_in[7];
    const float* W2d   = (const float*)d_in[8];
    const float* att2s = (const float*)d_in[9];
    const float* att2d = (const float*)d_in[10];
    const float* b2    = (const float*)d_in[11];
    float* out = (float*)d_out;

    float* ws   = (float*)d_ws;
    float* h1   = ws;                                // N*256 (reused as h2: N*128)
    float* act2 = h1 + (size_t)N_NODES * HID;        // N*256
    float* a1s  = act2 + (size_t)N_NODES * HID;      // N
    float* a1d  = a1s + N_NODES;
    float* a2s  = a1d + N_NODES;
    float* a2d  = a2s + N_NODES;
    float* s1   = a2d + N_NODES;
    float* s2   = s1 + N_NODES;
    float* ex1  = s2 + N_NODES;                      // E
    float* ex2  = ex1 + N_EDGES;                     // E
    float* v1s  = ex2 + N_EDGES;                     // 256
    float* v1d  = v1s + HID;
    float* v2s  = v1d + HID;                         // 256
    float* v2d  = v2s + HID;
    float* h2   = h1;                                // overlay: h1 dead after layer-1 aggregate

    const int aggBlocks1 = (N_EDGES * 64 + 255) / 256 * 1;  // 4 waves (edges) per block
    const int waveBlocksN = (N_NODES + 3) / 4;              // 4 waves per 256-thr block

    // ---------------- layer 1 ----------------
    compute_v_kernel<<<HID, 64, 0, stream>>>(W1s, att1s, v1s, HID);
    compute_v_kernel<<<HID, 64, 0, stream>>>(W1d, att1d, v1d, HID);
    compute_a_kernel<<<waveBlocksN, 256, 0, stream>>>(x, v1s, v1d, a1s, a1d, N_NODES, HID);
    gemm_kernel<HID, HID, 32><<<(N_NODES + 31) / 32, HID, 0, stream>>>(x, W1s, h1, N_NODES);
    hipMemsetAsync(s1, 0, N_NODES * sizeof(float), stream);
    init_bias_kernel<HID><<<(N_NODES * HID + 255) / 256, 256, 0, stream>>>(act2, b1, N_NODES * HID);
    edge_softmax_kernel<<<(N_EDGES + 255) / 256, 256, 0, stream>>>(src, dst, a1s, a1d, ex1, s1);
    edge_aggregate_kernel<HID><<<(N_EDGES + 3) / 4, 256, 0, stream>>>(src, dst, ex1, s1, h1, act2);
    relu_kernel<<<(N_NODES * HID + 255) / 256, 256, 0, stream>>>(act2, N_NODES * HID);

    // ---------------- layer 2 ----------------
    compute_v_kernel<<<HID, 64, 0, stream>>>(W2s, att2s, v2s, OUT_C);
    compute_v_kernel<<<HID, 64, 0, stream>>>(W2d, att2d, v2d, OUT_C);
    compute_a_kernel<<<waveBlocksN, 256, 0, stream>>>(act2, v2s, v2d, a2s, a2d, N_NODES, HID);
    gemm_kernel<HID, OUT_C, 32><<<(N_NODES + 31) / 32, OUT_C, 0, stream>>>(act2, W2s, h2, N_NODES);
    hipMemsetAsync(s2, 0, N_NODES * sizeof(float), stream);
    init_bias_kernel<OUT_C><<<(N_NODES * OUT_C + 255) / 256, 256, 0, stream>>>(out, b2, N_NODES * OUT_C);
    edge_softmax_kernel<<<(N_EDGES + 255) / 256, 256, 0, stream>>>(src, dst, a2s, a2d, ex2, s2);
    edge_aggregate_kernel<OUT_C><<<(N_EDGES + 3) / 4, 256, 0, stream>>>(src, dst, ex2, s2, h2, out);
}

// Round 2
// 1211.402 us; speedup vs baseline: 3.2869x; 3.2869x over previous
//
#include <hip/hip_runtime.h>
#include <math.h>

#define N_NODES 50000
#define N_EDGES 800000
#define HID 256
#define OUT_C 128
#define NEG_SLOPE 0.2f

// ---------------- CSR build (per call; int atomics only) ----------------

__global__ __launch_bounds__(256) void hist_kernel(
    const int* __restrict__ dst, int* __restrict__ counts) {
    int e = blockIdx.x * 256 + threadIdx.x;
    if (e < N_EDGES) atomicAdd(&counts[dst[e]], 1);
}

// single-wave exclusive scan over counts[n] -> offsets[n+1]
__global__ __launch_bounds__(64) void scan_kernel(
    const int* __restrict__ counts, int* __restrict__ offsets, int n) {
    int lane = threadIdx.x;
    int run = 0;
    for (int base = 0; base < n; base += 64) {
        int i = base + lane;
        int c = (i < n) ? counts[i] : 0;
        int v = c;
        #pragma unroll
        for (int off = 1; off < 64; off <<= 1) {
            int t = __shfl_up(v, off);
            if (lane >= off) v += t;
        }
        if (i < n) offsets[i] = run + v - c;   // exclusive
        run += __shfl(v, 63);
    }
    if (lane == 0) offsets[n] = run;
}

// src_sorted[pos] = src[e], grouped by dst via cursor atomics
__global__ __launch_bounds__(256) void scatter_kernel(
    const int* __restrict__ src, const int* __restrict__ dst,
    const int* __restrict__ offsets, int* __restrict__ cursor,
    int* __restrict__ src_sorted) {
    int e = blockIdx.x * 256 + threadIdx.x;
    if (e >= N_EDGES) return;
    int d = dst[e];
    int pos = offsets[d] + atomicAdd(&cursor[d], 1);
    src_sorted[pos] = src[e];
}

// ---------------- small dense pieces ----------------

// v[k] = sum_j W[k][j] * att[j]
__global__ __launch_bounds__(64) void compute_v_kernel(
    const float* __restrict__ W, const float* __restrict__ att,
    float* __restrict__ v, int cout) {
    int k = blockIdx.x;
    int lane = threadIdx.x;
    float sum = 0.f;
    for (int j = lane; j < cout; j += 64)
        sum += W[k * cout + j] * att[j];
    #pragma unroll
    for (int off = 32; off > 0; off >>= 1)
        sum += __shfl_down(sum, off);
    if (lane == 0) v[k] = sum;
}

// a_src[n] = x[n,:].vsrc ; a_dst[n] = x[n,:].vdst (one wave per node)
__global__ __launch_bounds__(256) void compute_a_kernel(
    const float* __restrict__ x, const float* __restrict__ vsrc,
    const float* __restrict__ vdst, float* __restrict__ a_src,
    float* __restrict__ a_dst, int n, int c) {
    int wave = (int)((blockIdx.x * (unsigned)blockDim.x + threadIdx.x) >> 6);
    int lane = threadIdx.x & 63;
    if (wave >= n) return;
    const float* xr = x + (size_t)wave * c;
    float ss = 0.f, sd = 0.f;
    for (int j = lane; j < c; j += 64) {
        float xv = xr[j];
        ss += xv * vsrc[j];
        sd += xv * vdst[j];
    }
    #pragma unroll
    for (int off = 32; off > 0; off >>= 1) {
        ss += __shfl_down(ss, off);
        sd += __shfl_down(sd, off);
    }
    if (lane == 0) { a_src[wave] = ss; a_dst[wave] = sd; }
}

// H[n,:] = A[n,:] @ W  (fp32, LDS row tile, W coalesced from L2)
template <int CIN, int COUT, int TM>
__global__ __launch_bounds__(COUT) void gemm_kernel(
    const float* __restrict__ A, const float* __restrict__ W,
    float* __restrict__ H, int n) {
    __shared__ __align__(16) float xs[TM][CIN];
    int row0 = blockIdx.x * TM;
    int tid = threadIdx.x;
    const int total4 = TM * CIN / 4;
    float4* xs4 = (float4*)&xs[0][0];
    for (int i = tid; i < total4; i += COUT) {
        int elem = i * 4;
        int r = elem / CIN;
        int gr = row0 + r;
        float4 val = make_float4(0.f, 0.f, 0.f, 0.f);
        if (gr < n) val = *(const float4*)(A + (size_t)gr * CIN + (elem & (CIN - 1)));
        xs4[i] = val;
    }
    __syncthreads();
    float acc[TM];
    #pragma unroll
    for (int r = 0; r < TM; r++) acc[r] = 0.f;
    #pragma unroll 4
    for (int k = 0; k < CIN; k++) {
        float w = W[k * COUT + tid];
        #pragma unroll
        for (int r = 0; r < TM; r++)
            acc[r] += xs[r][k] * w;
    }
    #pragma unroll
    for (int r = 0; r < TM; r++) {
        int gr = row0 + r;
        if (gr < n) H[(size_t)gr * COUT + tid] = acc[r];
    }
}

// ---------------- edge softmax (CSR, no atomics) ----------------

// one thread per dst node: ex_sorted[e] = exp(lrelu(a_s[src]+a_d[d])), inv_s[d]=1/(sum+eps)
__global__ __launch_bounds__(256) void exsum_kernel(
    const int* __restrict__ offsets, const int* __restrict__ src_sorted,
    const float* __restrict__ a_src, const float* __restrict__ a_dst,
    float* __restrict__ ex_sorted, float* __restrict__ inv_s) {
    int d = blockIdx.x * 256 + threadIdx.x;
    if (d >= N_NODES) return;
    int beg = offsets[d], end = offsets[d + 1];
    float ad = a_dst[d];
    float s = 0.f;
    for (int e = beg; e < end; e++) {
        float logit = a_src[src_sorted[e]] + ad;
        if (logit < 0.f) logit *= NEG_SLOPE;
        float v = expf(logit);   // shift-invariant softmax; logits O(1..10)
        ex_sorted[e] = v;
        s += v;
    }
    inv_s[d] = 1.f / (s + 1e-16f);
}

// ---------------- aggregation: one wave per dst node, no atomics ----------------

template <int C, bool RELU>
__global__ __launch_bounds__(256) void aggregate_kernel(
    const int* __restrict__ offsets, const int* __restrict__ src_sorted,
    const float* __restrict__ ex_sorted, const float* __restrict__ inv_s,
    const float* __restrict__ h, const float* __restrict__ bias,
    float* __restrict__ out) {
    int node = (int)((blockIdx.x * 256u + threadIdx.x) >> 6);
    int lane = threadIdx.x & 63;
    if (node >= N_NODES) return;
    int beg = offsets[node], end = offsets[node + 1];
    float invs = inv_s[node];
    if (C == 256) {
        float4 acc = make_float4(0.f, 0.f, 0.f, 0.f);
        for (int e = beg; e < end; e++) {
            float w = ex_sorted[e] * invs;
            const float* hr = h + (size_t)src_sorted[e] * C;
            float4 hv = *(const float4*)(hr + lane * 4);
            acc.x += w * hv.x; acc.y += w * hv.y;
            acc.z += w * hv.z; acc.w += w * hv.w;
        }
        float4 bv = *(const float4*)(bias + lane * 4);
        acc.x += bv.x; acc.y += bv.y; acc.z += bv.z; acc.w += bv.w;
        if (RELU) {
            acc.x = fmaxf(acc.x, 0.f); acc.y = fmaxf(acc.y, 0.f);
            acc.z = fmaxf(acc.z, 0.f); acc.w = fmaxf(acc.w, 0.f);
        }
        *(float4*)(out + (size_t)node * C + lane * 4) = acc;
    } else {
        float2 acc = make_float2(0.f, 0.f);
        for (int e = beg; e < end; e++) {
            float w = ex_sorted[e] * invs;
            const float* hr = h + (size_t)src_sorted[e] * C;
            float2 hv = *(const float2*)(hr + lane * 2);
            acc.x += w * hv.x; acc.y += w * hv.y;
        }
        float2 bv = *(const float2*)(bias + lane * 2);
        acc.x += bv.x; acc.y += bv.y;
        if (RELU) { acc.x = fmaxf(acc.x, 0.f); acc.y = fmaxf(acc.y, 0.f); }
        *(float2*)(out + (size_t)node * C + lane * 2) = acc;
    }
}

extern "C" void kernel_launch(void* const* d_in, const int* in_sizes, int n_in,
                              void* d_out, int out_size, void* d_ws, size_t ws_size,
                              hipStream_t stream) {
    const float* x     = (const float*)d_in[0];
    const int*   edge  = (const int*)d_in[1];
    const int*   src   = edge;
    const int*   dst   = edge + N_EDGES;
    const float* W1s   = (const float*)d_in[2];
    const float* att1s = (const float*)d_in[4];
    const float* W1d   = (const float*)d_in[3];
    const float* att1d = (const float*)d_in[5];
    const float* b1    = (const float*)d_in[6];
    const float* W2s   = (const float*)d_in[7];
    const float* W2d   = (const float*)d_in[8];
    const float* att2s = (const float*)d_in[9];
    const float* att2d = (const float*)d_in[10];
    const float* b2    = (const float*)d_in[11];
    float* out = (float*)d_out;

    // -------- workspace layout (floats first, then ints) --------
    float* ws    = (float*)d_ws;
    float* h1    = ws;                                 // N*256  (reused as h2)
    float* act2  = h1 + (size_t)N_NODES * HID;         // N*256
    float* a_s   = act2 + (size_t)N_NODES * HID;       // N (reused both layers)
    float* a_d   = a_s + N_NODES;                      // N
    float* inv_s = a_d + N_NODES;                      // N
    float* ex    = inv_s + N_NODES;                    // E (reused both layers)
    float* vbuf  = ex + N_EDGES;                       // 4*256
    int* ibase      = (int*)(vbuf + 4 * HID);
    int* src_sorted = ibase;                           // E
    int* counts     = src_sorted + N_EDGES;            // N (also cursor)
    int* offsets    = counts + N_NODES;                // N+1
    float* v1s = vbuf, *v1d = vbuf + HID, *v2s = vbuf + 2 * HID, *v2d = vbuf + 3 * HID;
    float* h2 = h1;

    const int edgeBlocks = (N_EDGES + 255) / 256;
    const int nodeBlocks = (N_NODES + 255) / 256;
    const int waveBlocksN = (N_NODES + 3) / 4;   // 4 waves per 256-thr block

    // -------- CSR build (graph identical for both layers) --------
    hipMemsetAsync(counts, 0, N_NODES * sizeof(int), stream);
    hist_kernel<<<edgeBlocks, 256, 0, stream>>>(dst, counts);
    scan_kernel<<<1, 64, 0, stream>>>(counts, offsets, N_NODES);
    hipMemsetAsync(counts, 0, N_NODES * sizeof(int), stream);  // reuse as cursor
    scatter_kernel<<<edgeBlocks, 256, 0, stream>>>(src, dst, offsets, counts, src_sorted);

    // -------- layer 1 --------
    compute_v_kernel<<<HID, 64, 0, stream>>>(W1s, att1s, v1s, HID);
    compute_v_kernel<<<HID, 64, 0, stream>>>(W1d, att1d, v1d, HID);
    compute_a_kernel<<<waveBlocksN, 256, 0, stream>>>(x, v1s, v1d, a_s, a_d, N_NODES, HID);
    gemm_kernel<HID, HID, 32><<<(N_NODES + 31) / 32, HID, 0, stream>>>(x, W1s, h1, N_NODES);
    exsum_kernel<<<nodeBlocks, 256, 0, stream>>>(offsets, src_sorted, a_s, a_d, ex, inv_s);
    aggregate_kernel<HID, true><<<waveBlocksN, 256, 0, stream>>>(
        offsets, src_sorted, ex, inv_s, h1, b1, act2);

    // -------- layer 2 --------
    compute_v_kernel<<<HID, 64, 0, stream>>>(W2s, att2s, v2s, OUT_C);
    compute_v_kernel<<<HID, 64, 0, stream>>>(W2d, att2d, v2d, OUT_C);
    compute_a_kernel<<<waveBlocksN, 256, 0, stream>>>(act2, v2s, v2d, a_s, a_d, N_NODES, HID);
    gemm_kernel<HID, OUT_C, 32><<<(N_NODES + 31) / 32, OUT_C, 0, stream>>>(act2, W2s, h2, N_NODES);
    exsum_kernel<<<nodeBlocks, 256, 0, stream>>>(offsets, src_sorted, a_s, a_d, ex, inv_s);
    aggregate_kernel<OUT_C, false><<<waveBlocksN, 256, 0, stream>>>(
        offsets, src_sorted, ex, inv_s, h2, b2, out);
}

// Round 3
// 844.825 us; speedup vs baseline: 4.7131x; 1.4339x over previous
//
#include <hip/hip_runtime.h>
#include <math.h>

#define N_NODES 50000
#define N_EDGES 800000
#define HID 256
#define OUT_C 128
#define NEG_SLOPE 0.2f
#define SCAN_NB ((N_NODES + 255) / 256)   // 196

// ---------------- CSR build (per call; int atomics only) ----------------

__global__ __launch_bounds__(256) void hist_kernel(
    const int* __restrict__ dst, int* __restrict__ counts) {
    int e = blockIdx.x * 256 + threadIdx.x;
    if (e < N_EDGES) atomicAdd(&counts[dst[e]], 1);
}

// phase 1: per-block exclusive scan (256 elems) + block sums
__global__ __launch_bounds__(256) void block_scan_kernel(
    const int* __restrict__ counts, int* __restrict__ excl,
    int* __restrict__ blockSums, int n) {
    __shared__ int waveSums[4];
    int i = blockIdx.x * 256 + threadIdx.x;
    int lane = threadIdx.x & 63;
    int wv = threadIdx.x >> 6;
    int c = (i < n) ? counts[i] : 0;
    int v = c;
    #pragma unroll
    for (int off = 1; off < 64; off <<= 1) {
        int t = __shfl_up(v, off);
        if (lane >= off) v += t;
    }
    if (lane == 63) waveSums[wv] = v;
    __syncthreads();
    int waveOff = 0;
    #pragma unroll
    for (int w = 0; w < 4; w++)
        if (w < wv) waveOff += waveSums[w];
    if (i < n) excl[i] = waveOff + v - c;
    if (threadIdx.x == 255) blockSums[blockIdx.x] = waveOff + v;
}

// phase 2: single-wave exclusive scan over the (196) block sums, in place
__global__ __launch_bounds__(64) void scan_sums_kernel(
    int* __restrict__ blockSums, int nb) {
    int lane = threadIdx.x;
    int run = 0;
    for (int base = 0; base < nb; base += 64) {
        int i = base + lane;
        int c = (i < nb) ? blockSums[i] : 0;
        int v = c;
        #pragma unroll
        for (int off = 1; off < 64; off <<= 1) {
            int t = __shfl_up(v, off);
            if (lane >= off) v += t;
        }
        if (i < nb) blockSums[i] = run + v - c;   // exclusive
        run += __shfl(v, 63);
    }
}

// phase 3: uniform add; also writes offsets[n] = total edge count
__global__ __launch_bounds__(256) void add_offsets_kernel(
    int* __restrict__ excl, const int* __restrict__ blockSums, int n) {
    int i = blockIdx.x * 256 + threadIdx.x;
    if (i < n) excl[i] += blockSums[blockIdx.x];
    if (i == 0) excl[n] = N_EDGES;
}

// src_sorted[pos] = src[e], grouped by dst via cursor atomics
__global__ __launch_bounds__(256) void scatter_kernel(
    const int* __restrict__ src, const int* __restrict__ dst,
    const int* __restrict__ offsets, int* __restrict__ cursor,
    int* __restrict__ src_sorted) {
    int e = blockIdx.x * 256 + threadIdx.x;
    if (e >= N_EDGES) return;
    int d = dst[e];
    int pos = offsets[d] + atomicAdd(&cursor[d], 1);
    src_sorted[pos] = src[e];
}

// ---------------- small dense pieces ----------------

// v[k] = sum_j W[k][j] * att[j]
__global__ __launch_bounds__(64) void compute_v_kernel(
    const float* __restrict__ W, const float* __restrict__ att,
    float* __restrict__ v, int cout) {
    int k = blockIdx.x;
    int lane = threadIdx.x;
    float sum = 0.f;
    for (int j = lane; j < cout; j += 64)
        sum += W[k * cout + j] * att[j];
    #pragma unroll
    for (int off = 32; off > 0; off >>= 1)
        sum += __shfl_down(sum, off);
    if (lane == 0) v[k] = sum;
}

// a_src[n] = x[n,:].vsrc ; a_dst[n] = x[n,:].vdst (one wave per node)
__global__ __launch_bounds__(256) void compute_a_kernel(
    const float* __restrict__ x, const float* __restrict__ vsrc,
    const float* __restrict__ vdst, float* __restrict__ a_src,
    float* __restrict__ a_dst, int n, int c) {
    int wave = (int)((blockIdx.x * (unsigned)blockDim.x + threadIdx.x) >> 6);
    int lane = threadIdx.x & 63;
    if (wave >= n) return;
    const float* xr = x + (size_t)wave * c;
    float ss = 0.f, sd = 0.f;
    for (int j = lane; j < c; j += 64) {
        float xv = xr[j];
        ss += xv * vsrc[j];
        sd += xv * vdst[j];
    }
    #pragma unroll
    for (int off = 32; off > 0; off >>= 1) {
        ss += __shfl_down(ss, off);
        sd += __shfl_down(sd, off);
    }
    if (lane == 0) { a_src[wave] = ss; a_dst[wave] = sd; }
}

// H[n,:] = A[n,:] @ W  (fp32, LDS row tile, W coalesced from L2)
template <int CIN, int COUT, int TM>
__global__ __launch_bounds__(COUT) void gemm_kernel(
    const float* __restrict__ A, const float* __restrict__ W,
    float* __restrict__ H, int n) {
    __shared__ __align__(16) float xs[TM][CIN];
    int row0 = blockIdx.x * TM;
    int tid = threadIdx.x;
    const int total4 = TM * CIN / 4;
    float4* xs4 = (float4*)&xs[0][0];
    for (int i = tid; i < total4; i += COUT) {
        int elem = i * 4;
        int r = elem / CIN;
        int gr = row0 + r;
        float4 val = make_float4(0.f, 0.f, 0.f, 0.f);
        if (gr < n) val = *(const float4*)(A + (size_t)gr * CIN + (elem & (CIN - 1)));
        xs4[i] = val;
    }
    __syncthreads();
    float acc[TM];
    #pragma unroll
    for (int r = 0; r < TM; r++) acc[r] = 0.f;
    #pragma unroll 4
    for (int k = 0; k < CIN; k++) {
        float w = W[k * COUT + tid];
        #pragma unroll
        for (int r = 0; r < TM; r++)
            acc[r] += xs[r][k] * w;
    }
    #pragma unroll
    for (int r = 0; r < TM; r++) {
        int gr = row0 + r;
        if (gr < n) H[(size_t)gr * COUT + tid] = acc[r];
    }
}

// ---------------- edge softmax (CSR, no atomics) ----------------

__global__ __launch_bounds__(256) void exsum_kernel(
    const int* __restrict__ offsets, const int* __restrict__ src_sorted,
    const float* __restrict__ a_src, const float* __restrict__ a_dst,
    float* __restrict__ ex_sorted, float* __restrict__ inv_s) {
    int d = blockIdx.x * 256 + threadIdx.x;
    if (d >= N_NODES) return;
    int beg = offsets[d], end = offsets[d + 1];
    float ad = a_dst[d];
    float s = 0.f;
    for (int e = beg; e < end; e++) {
        float logit = a_src[src_sorted[e]] + ad;
        if (logit < 0.f) logit *= NEG_SLOPE;
        float v = expf(logit);   // shift-invariant softmax; logits O(1..10)
        ex_sorted[e] = v;
        s += v;
    }
    inv_s[d] = 1.f / (s + 1e-16f);
}

// ---------------- aggregation: one wave per dst node, no atomics ----------------

template <int C, bool RELU>
__global__ __launch_bounds__(256) void aggregate_kernel(
    const int* __restrict__ offsets, const int* __restrict__ src_sorted,
    const float* __restrict__ ex_sorted, const float* __restrict__ inv_s,
    const float* __restrict__ h, const float* __restrict__ bias,
    float* __restrict__ out) {
    int node = (int)((blockIdx.x * 256u + threadIdx.x) >> 6);
    int lane = threadIdx.x & 63;
    if (node >= N_NODES) return;
    int beg = offsets[node], end = offsets[node + 1];
    float invs = inv_s[node];
    if (C == 256) {
        float4 acc = make_float4(0.f, 0.f, 0.f, 0.f);
        for (int e = beg; e < end; e++) {
            float w = ex_sorted[e] * invs;
            const float* hr = h + (size_t)src_sorted[e] * C;
            float4 hv = *(const float4*)(hr + lane * 4);
            acc.x += w * hv.x; acc.y += w * hv.y;
            acc.z += w * hv.z; acc.w += w * hv.w;
        }
        float4 bv = *(const float4*)(bias + lane * 4);
        acc.x += bv.x; acc.y += bv.y; acc.z += bv.z; acc.w += bv.w;
        if (RELU) {
            acc.x = fmaxf(acc.x, 0.f); acc.y = fmaxf(acc.y, 0.f);
            acc.z = fmaxf(acc.z, 0.f); acc.w = fmaxf(acc.w, 0.f);
        }
        *(float4*)(out + (size_t)node * C + lane * 4) = acc;
    } else {
        float2 acc = make_float2(0.f, 0.f);
        for (int e = beg; e < end; e++) {
            float w = ex_sorted[e] * invs;
            const float* hr = h + (size_t)src_sorted[e] * C;
            float2 hv = *(const float2*)(hr + lane * 2);
            acc.x += w * hv.x; acc.y += w * hv.y;
        }
        float2 bv = *(const float2*)(bias + lane * 2);
        acc.x += bv.x; acc.y += bv.y;
        if (RELU) { acc.x = fmaxf(acc.x, 0.f); acc.y = fmaxf(acc.y, 0.f); }
        *(float2*)(out + (size_t)node * C + lane * 2) = acc;
    }
}

extern "C" void kernel_launch(void* const* d_in, const int* in_sizes, int n_in,
                              void* d_out, int out_size, void* d_ws, size_t ws_size,
                              hipStream_t stream) {
    const float* x     = (const float*)d_in[0];
    const int*   edge  = (const int*)d_in[1];
    const int*   src   = edge;
    const int*   dst   = edge + N_EDGES;
    const float* W1s   = (const float*)d_in[2];
    const float* W1d   = (const float*)d_in[3];
    const float* att1s = (const float*)d_in[4];
    const float* att1d = (const float*)d_in[5];
    const float* b1    = (const float*)d_in[6];
    const float* W2s   = (const float*)d_in[7];
    const float* W2d   = (const float*)d_in[8];
    const float* att2s = (const float*)d_in[9];
    const float* att2d = (const float*)d_in[10];
    const float* b2    = (const float*)d_in[11];
    float* out = (float*)d_out;

    // -------- workspace layout (floats first, then ints) --------
    float* ws    = (float*)d_ws;
    float* h1    = ws;                                 // N*256  (reused as h2)
    float* act2  = h1 + (size_t)N_NODES * HID;         // N*256
    float* a_s   = act2 + (size_t)N_NODES * HID;       // N
    float* a_d   = a_s + N_NODES;                      // N
    float* inv_s = a_d + N_NODES;                      // N
    float* ex    = inv_s + N_NODES;                    // E
    float* vbuf  = ex + N_EDGES;                       // 4*256
    int* ibase      = (int*)(vbuf + 4 * HID);
    int* src_sorted = ibase;                           // E
    int* counts     = src_sorted + N_EDGES;            // N (also cursor)
    int* offsets    = counts + N_NODES;                // N+1
    int* blockSums  = offsets + N_NODES + 1;           // SCAN_NB
    float* v1s = vbuf, *v1d = vbuf + HID, *v2s = vbuf + 2 * HID, *v2d = vbuf + 3 * HID;
    float* h2 = h1;

    const int edgeBlocks = (N_EDGES + 255) / 256;
    const int nodeBlocks = (N_NODES + 255) / 256;
    const int waveBlocksN = (N_NODES + 3) / 4;   // 4 waves per 256-thr block

    // -------- CSR build (graph identical for both layers) --------
    hipMemsetAsync(counts, 0, N_NODES * sizeof(int), stream);
    hist_kernel<<<edgeBlocks, 256, 0, stream>>>(dst, counts);
    block_scan_kernel<<<SCAN_NB, 256, 0, stream>>>(counts, offsets, blockSums, N_NODES);
    scan_sums_kernel<<<1, 64, 0, stream>>>(blockSums, SCAN_NB);
    add_offsets_kernel<<<SCAN_NB, 256, 0, stream>>>(offsets, blockSums, N_NODES);
    hipMemsetAsync(counts, 0, N_NODES * sizeof(int), stream);  // reuse as cursor
    scatter_kernel<<<edgeBlocks, 256, 0, stream>>>(src, dst, offsets, counts, src_sorted);

    // -------- layer 1 --------
    compute_v_kernel<<<HID, 64, 0, stream>>>(W1s, att1s, v1s, HID);
    compute_v_kernel<<<HID, 64, 0, stream>>>(W1d, att1d, v1d, HID);
    compute_a_kernel<<<waveBlocksN, 256, 0, stream>>>(x, v1s, v1d, a_s, a_d, N_NODES, HID);
    gemm_kernel<HID, HID, 32><<<(N_NODES + 31) / 32, HID, 0, stream>>>(x, W1s, h1, N_NODES);
    exsum_kernel<<<nodeBlocks, 256, 0, stream>>>(offsets, src_sorted, a_s, a_d, ex, inv_s);
    aggregate_kernel<HID, true><<<waveBlocksN, 256, 0, stream>>>(
        offsets, src_sorted, ex, inv_s, h1, b1, act2);

    // -------- layer 2 --------
    compute_v_kernel<<<HID, 64, 0, stream>>>(W2s, att2s, v2s, OUT_C);
    compute_v_kernel<<<HID, 64, 0, stream>>>(W2d, att2d, v2d, OUT_C);
    compute_a_kernel<<<waveBlocksN, 256, 0, stream>>>(act2, v2s, v2d, a_s, a_d, N_NODES, HID);
    gemm_kernel<HID, OUT_C, 32><<<(N_NODES + 31) / 32, OUT_C, 0, stream>>>(act2, W2s, h2, N_NODES);
    exsum_kernel<<<nodeBlocks, 256, 0, stream>>>(offsets, src_sorted, a_s, a_d, ex, inv_s);
    aggregate_kernel<OUT_C, false><<<waveBlocksN, 256, 0, stream>>>(
        offsets, src_sorted, ex, inv_s, h2, b2, out);
}

// Round 4
// 529.414 us; speedup vs baseline: 7.5210x; 1.5958x over previous
//
#include <hip/hip_runtime.h>
#include <math.h>

#define N_NODES 50000
#define N_EDGES 800000
#define HID 256
#define OUT_C 128
#define NEG_SLOPE 0.2f
#define SCAN_NB ((N_NODES + 255) / 256)   // 196

typedef __attribute__((ext_vector_type(8))) short bf16x8;   // 8 bf16 (4 VGPRs)
typedef __attribute__((ext_vector_type(4))) float f32x4;    // MFMA C/D

__device__ inline unsigned short bf16_rne(float x) {
    unsigned u = __float_as_uint(x);
    return (unsigned short)((u + 0x7fffu + ((u >> 16) & 1u)) >> 16);
}

// ---------------- CSR build (per call; int atomics only) ----------------

__global__ __launch_bounds__(256) void hist_kernel(
    const int* __restrict__ dst, int* __restrict__ counts) {
    int e = blockIdx.x * 256 + threadIdx.x;
    if (e < N_EDGES) atomicAdd(&counts[dst[e]], 1);
}

__global__ __launch_bounds__(256) void block_scan_kernel(
    const int* __restrict__ counts, int* __restrict__ excl,
    int* __restrict__ blockSums, int n) {
    __shared__ int waveSums[4];
    int i = blockIdx.x * 256 + threadIdx.x;
    int lane = threadIdx.x & 63;
    int wv = threadIdx.x >> 6;
    int c = (i < n) ? counts[i] : 0;
    int v = c;
    #pragma unroll
    for (int off = 1; off < 64; off <<= 1) {
        int t = __shfl_up(v, off);
        if (lane >= off) v += t;
    }
    if (lane == 63) waveSums[wv] = v;
    __syncthreads();
    int waveOff = 0;
    #pragma unroll
    for (int w = 0; w < 4; w++)
        if (w < wv) waveOff += waveSums[w];
    if (i < n) excl[i] = waveOff + v - c;
    if (threadIdx.x == 255) blockSums[blockIdx.x] = waveOff + v;
}

__global__ __launch_bounds__(64) void scan_sums_kernel(
    int* __restrict__ blockSums, int nb) {
    int lane = threadIdx.x;
    int run = 0;
    for (int base = 0; base < nb; base += 64) {
        int i = base + lane;
        int c = (i < nb) ? blockSums[i] : 0;
        int v = c;
        #pragma unroll
        for (int off = 1; off < 64; off <<= 1) {
            int t = __shfl_up(v, off);
            if (lane >= off) v += t;
        }
        if (i < nb) blockSums[i] = run + v - c;
        run += __shfl(v, 63);
    }
}

__global__ __launch_bounds__(256) void add_offsets_kernel(
    int* __restrict__ excl, const int* __restrict__ blockSums, int n) {
    int i = blockIdx.x * 256 + threadIdx.x;
    if (i < n) excl[i] += blockSums[blockIdx.x];
    if (i == 0) excl[n] = N_EDGES;
}

__global__ __launch_bounds__(256) void scatter_kernel(
    const int* __restrict__ src, const int* __restrict__ dst,
    const int* __restrict__ offsets, int* __restrict__ cursor,
    int* __restrict__ src_sorted) {
    int e = blockIdx.x * 256 + threadIdx.x;
    if (e >= N_EDGES) return;
    int d = dst[e];
    int pos = offsets[d] + atomicAdd(&cursor[d], 1);
    src_sorted[pos] = src[e];
}

// ---------------- small dense pieces ----------------

__global__ __launch_bounds__(64) void compute_v_kernel(
    const float* __restrict__ W, const float* __restrict__ att,
    float* __restrict__ v, int cout) {
    int k = blockIdx.x;
    int lane = threadIdx.x;
    float sum = 0.f;
    for (int j = lane; j < cout; j += 64)
        sum += W[k * cout + j] * att[j];
    #pragma unroll
    for (int off = 32; off > 0; off >>= 1)
        sum += __shfl_down(sum, off);
    if (lane == 0) v[k] = sum;
}

__global__ __launch_bounds__(256) void compute_a_kernel(
    const float* __restrict__ x, const float* __restrict__ vsrc,
    const float* __restrict__ vdst, float* __restrict__ a_src,
    float* __restrict__ a_dst, int n, int c) {
    int wave = (int)((blockIdx.x * (unsigned)blockDim.x + threadIdx.x) >> 6);
    int lane = threadIdx.x & 63;
    if (wave >= n) return;
    const float* xr = x + (size_t)wave * c;
    float ss = 0.f, sd = 0.f;
    for (int j = lane; j < c; j += 64) {
        float xv = xr[j];
        ss += xv * vsrc[j];
        sd += xv * vdst[j];
    }
    #pragma unroll
    for (int off = 32; off > 0; off >>= 1) {
        ss += __shfl_down(ss, off);
        sd += __shfl_down(sd, off);
    }
    if (lane == 0) { a_src[wave] = ss; a_dst[wave] = sd; }
}

// ---------------- W pre-pack into B-fragment layout (hi/lo bf16) ----------------
// frag t = (ks*(cout/16) + nt)*64 + lane; element j: W[ks*32 + (lane>>4)*8 + j][nt*16 + (lane&15)]

__global__ __launch_bounds__(256) void pack_w_kernel(
    const float* __restrict__ W, unsigned short* __restrict__ hi,
    unsigned short* __restrict__ lo, int cout) {
    int t = blockIdx.x * 256 + threadIdx.x;
    int total = 8 * (cout / 16) * 64;   // K=256 fixed -> 8 k-steps
    if (t >= total) return;
    int lane = t & 63;
    int nt = (t >> 6) % (cout / 16);
    int ks = t / (64 * (cout / 16));
    int n = nt * 16 + (lane & 15);
    int kbase = ks * 32 + ((lane >> 4) & 3) * 8;
    #pragma unroll
    for (int j = 0; j < 8; j++) {
        float v = W[(kbase + j) * cout + n];
        unsigned short h = bf16_rne(v);
        hi[t * 8 + j] = h;
        lo[t * 8 + j] = bf16_rne(v - __uint_as_float((unsigned)h << 16));
    }
}

// ---------------- MFMA GEMM: H = A @ W, fp32 via bf16 hi/lo split ----------------
// block = 4 waves; wave handles 32 rows x 128 cols; grid = (ceil(M/128), COUT/128)

template <int COUT>
__global__ __launch_bounds__(256) void mfma_gemm_kernel(
    const float* __restrict__ A, const unsigned short* __restrict__ Bhi,
    const unsigned short* __restrict__ Blo, float* __restrict__ H, int M) {
    const int NT = 8;
    int wave = threadIdx.x >> 6, lane = threadIdx.x & 63;
    int m = lane & 15, quad = lane >> 4;
    int row0 = blockIdx.x * 128 + wave * 32;
    int col0 = blockIdx.y * 128;
    f32x4 acc[2][NT];
    #pragma unroll
    for (int rg = 0; rg < 2; rg++)
        #pragma unroll
        for (int nt = 0; nt < NT; nt++)
            acc[rg][nt] = (f32x4){0.f, 0.f, 0.f, 0.f};

    for (int ks = 0; ks < 8; ks++) {
        bf16x8 ah[2], al[2];
        #pragma unroll
        for (int rg = 0; rg < 2; rg++) {
            int r = row0 + rg * 16 + m;
            if (r >= M) r = M - 1;          // clamp: pad rows never stored
            const float* ap = A + (size_t)r * HID + ks * 32 + quad * 8;
            float4 v0 = *(const float4*)ap;
            float4 v1 = *(const float4*)(ap + 4);
            float av[8] = {v0.x, v0.y, v0.z, v0.w, v1.x, v1.y, v1.z, v1.w};
            #pragma unroll
            for (int j = 0; j < 8; j++) {
                unsigned short h = bf16_rne(av[j]);
                float hf = __uint_as_float((unsigned)h << 16);
                ah[rg][j] = (short)h;
                al[rg][j] = (short)bf16_rne(av[j] - hf);
            }
        }
        size_t fbase = ((size_t)(ks * (COUT / 16) + (col0 >> 4)) * 64 + lane) * 8;
        const unsigned short* bp = Bhi + fbase;
        const unsigned short* bq = Blo + fbase;
        #pragma unroll
        for (int nt = 0; nt < NT; nt++) {
            bf16x8 bh = *(const bf16x8*)(bp + nt * 512);
            bf16x8 bl = *(const bf16x8*)(bq + nt * 512);
            acc[0][nt] = __builtin_amdgcn_mfma_f32_16x16x32_bf16(ah[0], bh, acc[0][nt], 0, 0, 0);
            acc[1][nt] = __builtin_amdgcn_mfma_f32_16x16x32_bf16(ah[1], bh, acc[1][nt], 0, 0, 0);
            acc[0][nt] = __builtin_amdgcn_mfma_f32_16x16x32_bf16(ah[0], bl, acc[0][nt], 0, 0, 0);
            acc[1][nt] = __builtin_amdgcn_mfma_f32_16x16x32_bf16(ah[1], bl, acc[1][nt], 0, 0, 0);
            acc[0][nt] = __builtin_amdgcn_mfma_f32_16x16x32_bf16(al[0], bh, acc[0][nt], 0, 0, 0);
            acc[1][nt] = __builtin_amdgcn_mfma_f32_16x16x32_bf16(al[1], bh, acc[1][nt], 0, 0, 0);
        }
    }
    // C/D layout: col = lane&15, row = quad*4 + reg  [m89-verified]
    #pragma unroll
    for (int rg = 0; rg < 2; rg++)
        #pragma unroll
        for (int nt = 0; nt < NT; nt++)
            #pragma unroll
            for (int r = 0; r < 4; r++) {
                int row = row0 + rg * 16 + quad * 4 + r;
                if (row < M)
                    H[(size_t)row * COUT + col0 + nt * 16 + m] = acc[rg][nt][r];
            }
}

// ---------------- edge softmax (CSR, no atomics) ----------------

__global__ __launch_bounds__(256) void exsum_kernel(
    const int* __restrict__ offsets, const int* __restrict__ src_sorted,
    const float* __restrict__ a_src, const float* __restrict__ a_dst,
    float* __restrict__ ex_sorted, float* __restrict__ inv_s) {
    int d = blockIdx.x * 256 + threadIdx.x;
    if (d >= N_NODES) return;
    int beg = offsets[d], end = offsets[d + 1];
    float ad = a_dst[d];
    float s = 0.f;
    for (int e = beg; e < end; e++) {
        float logit = a_src[src_sorted[e]] + ad;
        if (logit < 0.f) logit *= NEG_SLOPE;
        float v = expf(logit);
        ex_sorted[e] = v;
        s += v;
    }
    inv_s[d] = 1.f / (s + 1e-16f);
}

// ---------------- aggregation: one wave per dst node, no atomics ----------------

template <int C, bool RELU>
__global__ __launch_bounds__(256) void aggregate_kernel(
    const int* __restrict__ offsets, const int* __restrict__ src_sorted,
    const float* __restrict__ ex_sorted, const float* __restrict__ inv_s,
    const float* __restrict__ h, const float* __restrict__ bias,
    float* __restrict__ out) {
    int node = (int)((blockIdx.x * 256u + threadIdx.x) >> 6);
    int lane = threadIdx.x & 63;
    if (node >= N_NODES) return;
    int beg = offsets[node], end = offsets[node + 1];
    float invs = inv_s[node];
    if (C == 256) {
        float4 acc = make_float4(0.f, 0.f, 0.f, 0.f);
        for (int e = beg; e < end; e++) {
            float w = ex_sorted[e] * invs;
            const float* hr = h + (size_t)src_sorted[e] * C;
            float4 hv = *(const float4*)(hr + lane * 4);
            acc.x += w * hv.x; acc.y += w * hv.y;
            acc.z += w * hv.z; acc.w += w * hv.w;
        }
        float4 bv = *(const float4*)(bias + lane * 4);
        acc.x += bv.x; acc.y += bv.y; acc.z += bv.z; acc.w += bv.w;
        if (RELU) {
            acc.x = fmaxf(acc.x, 0.f); acc.y = fmaxf(acc.y, 0.f);
            acc.z = fmaxf(acc.z, 0.f); acc.w = fmaxf(acc.w, 0.f);
        }
        *(float4*)(out + (size_t)node * C + lane * 4) = acc;
    } else {
        float2 acc = make_float2(0.f, 0.f);
        for (int e = beg; e < end; e++) {
            float w = ex_sorted[e] * invs;
            const float* hr = h + (size_t)src_sorted[e] * C;
            float2 hv = *(const float2*)(hr + lane * 2);
            acc.x += w * hv.x; acc.y += w * hv.y;
        }
        float2 bv = *(const float2*)(bias + lane * 2);
        acc.x += bv.x; acc.y += bv.y;
        if (RELU) { acc.x = fmaxf(acc.x, 0.f); acc.y = fmaxf(acc.y, 0.f); }
        *(float2*)(out + (size_t)node * C + lane * 2) = acc;
    }
}

extern "C" void kernel_launch(void* const* d_in, const int* in_sizes, int n_in,
                              void* d_out, int out_size, void* d_ws, size_t ws_size,
                              hipStream_t stream) {
    const float* x     = (const float*)d_in[0];
    const int*   edge  = (const int*)d_in[1];
    const int*   src   = edge;
    const int*   dst   = edge + N_EDGES;
    const float* W1s   = (const float*)d_in[2];
    const float* W1d   = (const float*)d_in[3];
    const float* att1s = (const float*)d_in[4];
    const float* att1d = (const float*)d_in[5];
    const float* b1    = (const float*)d_in[6];
    const float* W2s   = (const float*)d_in[7];
    const float* W2d   = (const float*)d_in[8];
    const float* att2s = (const float*)d_in[9];
    const float* att2d = (const float*)d_in[10];
    const float* b2    = (const float*)d_in[11];
    float* out = (float*)d_out;

    // -------- workspace layout --------
    float* ws    = (float*)d_ws;
    float* h1    = ws;                                 // N*256  (reused as h2)
    float* act2  = h1 + (size_t)N_NODES * HID;         // N*256
    float* a_s   = act2 + (size_t)N_NODES * HID;       // N
    float* a_d   = a_s + N_NODES;                      // N
    float* inv_s = a_d + N_NODES;                      // N
    float* ex    = inv_s + N_NODES;                    // E
    float* vbuf  = ex + N_EDGES;                       // 4*256
    int* ibase      = (int*)(vbuf + 4 * HID);
    int* src_sorted = ibase;                           // E
    int* counts     = src_sorted + N_EDGES;            // N (also cursor)
    int* offsets    = counts + N_NODES;                // N+1
    int* blockSums  = offsets + N_NODES + 1;           // SCAN_NB
    // packed W fragments (hi/lo), 16B-aligned
    unsigned short* wp1h = (unsigned short*)(((uintptr_t)(blockSums + SCAN_NB) + 15) & ~(uintptr_t)15);
    unsigned short* wp1l = wp1h + 65536;               // 256*256
    unsigned short* wp2h = wp1l + 65536;
    unsigned short* wp2l = wp2h + 32768;               // 256*128
    float* v1s = vbuf, *v1d = vbuf + HID, *v2s = vbuf + 2 * HID, *v2d = vbuf + 3 * HID;
    float* h2 = h1;

    const int edgeBlocks = (N_EDGES + 255) / 256;
    const int nodeBlocks = (N_NODES + 255) / 256;
    const int waveBlocksN = (N_NODES + 3) / 4;
    const int gemmBlocks = (N_NODES + 127) / 128;      // 391

    // -------- CSR build --------
    hipMemsetAsync(counts, 0, N_NODES * sizeof(int), stream);
    hist_kernel<<<edgeBlocks, 256, 0, stream>>>(dst, counts);
    block_scan_kernel<<<SCAN_NB, 256, 0, stream>>>(counts, offsets, blockSums, N_NODES);
    scan_sums_kernel<<<1, 64, 0, stream>>>(blockSums, SCAN_NB);
    add_offsets_kernel<<<SCAN_NB, 256, 0, stream>>>(offsets, blockSums, N_NODES);
    hipMemsetAsync(counts, 0, N_NODES * sizeof(int), stream);
    scatter_kernel<<<edgeBlocks, 256, 0, stream>>>(src, dst, offsets, counts, src_sorted);

    // -------- W packing (both layers) --------
    pack_w_kernel<<<32, 256, 0, stream>>>(W1s, wp1h, wp1l, HID);
    pack_w_kernel<<<16, 256, 0, stream>>>(W2s, wp2h, wp2l, OUT_C);

    // -------- layer 1 --------
    compute_v_kernel<<<HID, 64, 0, stream>>>(W1s, att1s, v1s, HID);
    compute_v_kernel<<<HID, 64, 0, stream>>>(W1d, att1d, v1d, HID);
    compute_a_kernel<<<waveBlocksN, 256, 0, stream>>>(x, v1s, v1d, a_s, a_d, N_NODES, HID);
    mfma_gemm_kernel<HID><<<dim3(gemmBlocks, 2), 256, 0, stream>>>(x, wp1h, wp1l, h1, N_NODES);
    exsum_kernel<<<nodeBlocks, 256, 0, stream>>>(offsets, src_sorted, a_s, a_d, ex, inv_s);
    aggregate_kernel<HID, true><<<waveBlocksN, 256, 0, stream>>>(
        offsets, src_sorted, ex, inv_s, h1, b1, act2);

    // -------- layer 2 --------
    compute_v_kernel<<<HID, 64, 0, stream>>>(W2s, att2s, v2s, OUT_C);
    compute_v_kernel<<<HID, 64, 0, stream>>>(W2d, att2d, v2d, OUT_C);
    compute_a_kernel<<<waveBlocksN, 256, 0, stream>>>(act2, v2s, v2d, a_s, a_d, N_NODES, HID);
    mfma_gemm_kernel<OUT_C><<<dim3(gemmBlocks, 1), 256, 0, stream>>>(act2, wp2h, wp2l, h2, N_NODES);
    exsum_kernel<<<nodeBlocks, 256, 0, stream>>>(offsets, src_sorted, a_s, a_d, ex, inv_s);
    aggregate_kernel<OUT_C, false><<<waveBlocksN, 256, 0, stream>>>(
        offsets, src_sorted, ex, inv_s, h2, b2, out);
}

// Round 5
// 470.386 us; speedup vs baseline: 8.4648x; 1.1255x over previous
//
#include <hip/hip_runtime.h>
#include <math.h>

#define N_NODES 50000
#define N_EDGES 800000
#define HID 256
#define OUT_C 128
#define NEG_SLOPE 0.2f
#define SCAN_NB ((N_NODES + 255) / 256)   // 196

typedef __attribute__((ext_vector_type(8))) short bf16x8;   // 8 bf16 (4 VGPRs)
typedef __attribute__((ext_vector_type(4))) float f32x4;    // MFMA C/D

__device__ inline unsigned short bf16_rne(float x) {
    unsigned u = __float_as_uint(x);
    return (unsigned short)((u + 0x7fffu + ((u >> 16) & 1u)) >> 16);
}

// ---------------- CSR build (per call; int atomics only) ----------------

__global__ __launch_bounds__(256) void hist_kernel(
    const int* __restrict__ dst, int* __restrict__ counts) {
    int e = blockIdx.x * 256 + threadIdx.x;
    if (e < N_EDGES) atomicAdd(&counts[dst[e]], 1);
}

__global__ __launch_bounds__(256) void block_scan_kernel(
    const int* __restrict__ counts, int* __restrict__ excl,
    int* __restrict__ blockSums, int n) {
    __shared__ int waveSums[4];
    int i = blockIdx.x * 256 + threadIdx.x;
    int lane = threadIdx.x & 63;
    int wv = threadIdx.x >> 6;
    int c = (i < n) ? counts[i] : 0;
    int v = c;
    #pragma unroll
    for (int off = 1; off < 64; off <<= 1) {
        int t = __shfl_up(v, off);
        if (lane >= off) v += t;
    }
    if (lane == 63) waveSums[wv] = v;
    __syncthreads();
    int waveOff = 0;
    #pragma unroll
    for (int w = 0; w < 4; w++)
        if (w < wv) waveOff += waveSums[w];
    if (i < n) excl[i] = waveOff + v - c;
    if (threadIdx.x == 255) blockSums[blockIdx.x] = waveOff + v;
}

__global__ __launch_bounds__(64) void scan_sums_kernel(
    int* __restrict__ blockSums, int nb) {
    int lane = threadIdx.x;
    int run = 0;
    for (int base = 0; base < nb; base += 64) {
        int i = base + lane;
        int c = (i < nb) ? blockSums[i] : 0;
        int v = c;
        #pragma unroll
        for (int off = 1; off < 64; off <<= 1) {
            int t = __shfl_up(v, off);
            if (lane >= off) v += t;
        }
        if (i < nb) blockSums[i] = run + v - c;
        run += __shfl(v, 63);
    }
}

__global__ __launch_bounds__(256) void add_offsets_kernel(
    int* __restrict__ excl, const int* __restrict__ blockSums, int n) {
    int i = blockIdx.x * 256 + threadIdx.x;
    if (i < n) excl[i] += blockSums[blockIdx.x];
    if (i == 0) excl[n] = N_EDGES;
}

__global__ __launch_bounds__(256) void scatter_kernel(
    const int* __restrict__ src, const int* __restrict__ dst,
    const int* __restrict__ offsets, int* __restrict__ cursor,
    int* __restrict__ src_sorted) {
    int e = blockIdx.x * 256 + threadIdx.x;
    if (e >= N_EDGES) return;
    int d = dst[e];
    int pos = offsets[d] + atomicAdd(&cursor[d], 1);
    src_sorted[pos] = src[e];
}

// ---------------- small dense pieces ----------------

__global__ __launch_bounds__(64) void compute_v_kernel(
    const float* __restrict__ W, const float* __restrict__ att,
    float* __restrict__ v, int cout) {
    int k = blockIdx.x;
    int lane = threadIdx.x;
    float sum = 0.f;
    for (int j = lane; j < cout; j += 64)
        sum += W[k * cout + j] * att[j];
    #pragma unroll
    for (int off = 32; off > 0; off >>= 1)
        sum += __shfl_down(sum, off);
    if (lane == 0) v[k] = sum;
}

__global__ __launch_bounds__(256) void compute_a_kernel(
    const float* __restrict__ x, const float* __restrict__ vsrc,
    const float* __restrict__ vdst, float* __restrict__ a_src,
    float* __restrict__ a_dst, int n, int c) {
    int wave = (int)((blockIdx.x * (unsigned)blockDim.x + threadIdx.x) >> 6);
    int lane = threadIdx.x & 63;
    if (wave >= n) return;
    const float* xr = x + (size_t)wave * c;
    float ss = 0.f, sd = 0.f;
    for (int j = lane; j < c; j += 64) {
        float xv = xr[j];
        ss += xv * vsrc[j];
        sd += xv * vdst[j];
    }
    #pragma unroll
    for (int off = 32; off > 0; off >>= 1) {
        ss += __shfl_down(ss, off);
        sd += __shfl_down(sd, off);
    }
    if (lane == 0) { a_src[wave] = ss; a_dst[wave] = sd; }
}

// ---------------- W pre-pack into B-fragment layout (hi/lo bf16) ----------------

__global__ __launch_bounds__(256) void pack_w_kernel(
    const float* __restrict__ W, unsigned short* __restrict__ hi,
    unsigned short* __restrict__ lo, int cout) {
    int t = blockIdx.x * 256 + threadIdx.x;
    int total = 8 * (cout / 16) * 64;
    if (t >= total) return;
    int lane = t & 63;
    int nt = (t >> 6) % (cout / 16);
    int ks = t / (64 * (cout / 16));
    int n = nt * 16 + (lane & 15);
    int kbase = ks * 32 + ((lane >> 4) & 3) * 8;
    #pragma unroll
    for (int j = 0; j < 8; j++) {
        float v = W[(kbase + j) * cout + n];
        unsigned short h = bf16_rne(v);
        hi[t * 8 + j] = h;
        lo[t * 8 + j] = bf16_rne(v - __uint_as_float((unsigned)h << 16));
    }
}

// ---------------- MFMA GEMM: H = A @ W, fp32 via bf16 hi/lo split ----------------

template <int COUT>
__global__ __launch_bounds__(256) void mfma_gemm_kernel(
    const float* __restrict__ A, const unsigned short* __restrict__ Bhi,
    const unsigned short* __restrict__ Blo, float* __restrict__ H, int M) {
    const int NT = 8;
    int wave = threadIdx.x >> 6, lane = threadIdx.x & 63;
    int m = lane & 15, quad = lane >> 4;
    int row0 = blockIdx.x * 128 + wave * 32;
    int col0 = blockIdx.y * 128;
    f32x4 acc[2][NT];
    #pragma unroll
    for (int rg = 0; rg < 2; rg++)
        #pragma unroll
        for (int nt = 0; nt < NT; nt++)
            acc[rg][nt] = (f32x4){0.f, 0.f, 0.f, 0.f};

    for (int ks = 0; ks < 8; ks++) {
        bf16x8 ah[2], al[2];
        #pragma unroll
        for (int rg = 0; rg < 2; rg++) {
            int r = row0 + rg * 16 + m;
            if (r >= M) r = M - 1;
            const float* ap = A + (size_t)r * HID + ks * 32 + quad * 8;
            float4 v0 = *(const float4*)ap;
            float4 v1 = *(const float4*)(ap + 4);
            float av[8] = {v0.x, v0.y, v0.z, v0.w, v1.x, v1.y, v1.z, v1.w};
            #pragma unroll
            for (int j = 0; j < 8; j++) {
                unsigned short h = bf16_rne(av[j]);
                float hf = __uint_as_float((unsigned)h << 16);
                ah[rg][j] = (short)h;
                al[rg][j] = (short)bf16_rne(av[j] - hf);
            }
        }
        size_t fbase = ((size_t)(ks * (COUT / 16) + (col0 >> 4)) * 64 + lane) * 8;
        const unsigned short* bp = Bhi + fbase;
        const unsigned short* bq = Blo + fbase;
        #pragma unroll
        for (int nt = 0; nt < NT; nt++) {
            bf16x8 bh = *(const bf16x8*)(bp + nt * 512);
            bf16x8 bl = *(const bf16x8*)(bq + nt * 512);
            acc[0][nt] = __builtin_amdgcn_mfma_f32_16x16x32_bf16(ah[0], bh, acc[0][nt], 0, 0, 0);
            acc[1][nt] = __builtin_amdgcn_mfma_f32_16x16x32_bf16(ah[1], bh, acc[1][nt], 0, 0, 0);
            acc[0][nt] = __builtin_amdgcn_mfma_f32_16x16x32_bf16(ah[0], bl, acc[0][nt], 0, 0, 0);
            acc[1][nt] = __builtin_amdgcn_mfma_f32_16x16x32_bf16(ah[1], bl, acc[1][nt], 0, 0, 0);
            acc[0][nt] = __builtin_amdgcn_mfma_f32_16x16x32_bf16(al[0], bh, acc[0][nt], 0, 0, 0);
            acc[1][nt] = __builtin_amdgcn_mfma_f32_16x16x32_bf16(al[1], bh, acc[1][nt], 0, 0, 0);
        }
    }
    #pragma unroll
    for (int rg = 0; rg < 2; rg++)
        #pragma unroll
        for (int nt = 0; nt < NT; nt++)
            #pragma unroll
            for (int r = 0; r < 4; r++) {
                int row = row0 + rg * 16 + quad * 4 + r;
                if (row < M)
                    H[(size_t)row * COUT + col0 + nt * 16 + m] = acc[rg][nt][r];
            }
}

// ---------------- fused softmax + aggregation: one wave per dst node ----------------
// out[d,:] = (sum_e ex_e * h[src_e,:]) / (sum_e ex_e + eps) + bias,
// ex_e = exp(lrelu(a_src[src_e] + a_dst[d])). Chunked: 8 row-gathers in flight.

template <int C, bool RELU>
__global__ __launch_bounds__(256) void fused_aggregate_kernel(
    const int* __restrict__ offsets, const int* __restrict__ src_sorted,
    const float* __restrict__ a_src, const float* __restrict__ a_dst,
    const float* __restrict__ h, const float* __restrict__ bias,
    float* __restrict__ out) {
    constexpr int CH = 8;
    int node = (int)((blockIdx.x * 256u + threadIdx.x) >> 6);
    int lane = threadIdx.x & 63;
    if (node >= N_NODES) return;
    int beg = offsets[node], end = offsets[node + 1];
    float ad = a_dst[node];
    float s = 0.f;

    if (C == 256) {
        float4 acc = make_float4(0.f, 0.f, 0.f, 0.f);
        for (int base = beg; base < end; base += CH) {
            int cnt = end - base; if (cnt > CH) cnt = CH;
            int idx[CH];
            #pragma unroll
            for (int j = 0; j < CH; j++)
                idx[j] = src_sorted[(j < cnt) ? base + j : base];
            float4 hv[CH];
            #pragma unroll
            for (int j = 0; j < CH; j++)   // 8 independent 1KB gathers in flight
                hv[j] = *(const float4*)(h + (size_t)idx[j] * C + lane * 4);
            float w[CH];
            #pragma unroll
            for (int j = 0; j < CH; j++) { // overlaps with gathers (L2-resident a_src)
                float l = a_src[idx[j]] + ad;
                if (l < 0.f) l *= NEG_SLOPE;
                w[j] = (j < cnt) ? expf(l) : 0.f;
                s += w[j];
            }
            #pragma unroll
            for (int j = 0; j < CH; j++) {
                acc.x += w[j] * hv[j].x; acc.y += w[j] * hv[j].y;
                acc.z += w[j] * hv[j].z; acc.w += w[j] * hv[j].w;
            }
        }
        float inv = 1.f / (s + 1e-16f);
        float4 bv = *(const float4*)(bias + lane * 4);
        acc.x = acc.x * inv + bv.x; acc.y = acc.y * inv + bv.y;
        acc.z = acc.z * inv + bv.z; acc.w = acc.w * inv + bv.w;
        if (RELU) {
            acc.x = fmaxf(acc.x, 0.f); acc.y = fmaxf(acc.y, 0.f);
            acc.z = fmaxf(acc.z, 0.f); acc.w = fmaxf(acc.w, 0.f);
        }
        *(float4*)(out + (size_t)node * C + lane * 4) = acc;
    } else {
        float2 acc = make_float2(0.f, 0.f);
        for (int base = beg; base < end; base += CH) {
            int cnt = end - base; if (cnt > CH) cnt = CH;
            int idx[CH];
            #pragma unroll
            for (int j = 0; j < CH; j++)
                idx[j] = src_sorted[(j < cnt) ? base + j : base];
            float2 hv[CH];
            #pragma unroll
            for (int j = 0; j < CH; j++)
                hv[j] = *(const float2*)(h + (size_t)idx[j] * C + lane * 2);
            float w[CH];
            #pragma unroll
            for (int j = 0; j < CH; j++) {
                float l = a_src[idx[j]] + ad;
                if (l < 0.f) l *= NEG_SLOPE;
                w[j] = (j < cnt) ? expf(l) : 0.f;
                s += w[j];
            }
            #pragma unroll
            for (int j = 0; j < CH; j++) {
                acc.x += w[j] * hv[j].x; acc.y += w[j] * hv[j].y;
            }
        }
        float inv = 1.f / (s + 1e-16f);
        float2 bv = *(const float2*)(bias + lane * 2);
        acc.x = acc.x * inv + bv.x; acc.y = acc.y * inv + bv.y;
        if (RELU) { acc.x = fmaxf(acc.x, 0.f); acc.y = fmaxf(acc.y, 0.f); }
        *(float2*)(out + (size_t)node * C + lane * 2) = acc;
    }
}

extern "C" void kernel_launch(void* const* d_in, const int* in_sizes, int n_in,
                              void* d_out, int out_size, void* d_ws, size_t ws_size,
                              hipStream_t stream) {
    const float* x     = (const float*)d_in[0];
    const int*   edge  = (const int*)d_in[1];
    const int*   src   = edge;
    const int*   dst   = edge + N_EDGES;
    const float* W1s   = (const float*)d_in[2];
    const float* W1d   = (const float*)d_in[3];
    const float* att1s = (const float*)d_in[4];
    const float* att1d = (const float*)d_in[5];
    const float* b1    = (const float*)d_in[6];
    const float* W2s   = (const float*)d_in[7];
    const float* W2d   = (const float*)d_in[8];
    const float* att2s = (const float*)d_in[9];
    const float* att2d = (const float*)d_in[10];
    const float* b2    = (const float*)d_in[11];
    float* out = (float*)d_out;

    // -------- workspace layout --------
    float* ws    = (float*)d_ws;
    float* h1    = ws;                                 // N*256  (reused as h2)
    float* act2  = h1 + (size_t)N_NODES * HID;         // N*256
    float* a_s   = act2 + (size_t)N_NODES * HID;       // N
    float* a_d   = a_s + N_NODES;                      // N
    float* vbuf  = a_d + N_NODES;                      // 4*256
    int* ibase      = (int*)(vbuf + 4 * HID);
    int* src_sorted = ibase;                           // E
    int* counts     = src_sorted + N_EDGES;            // N (also cursor)
    int* offsets    = counts + N_NODES;                // N+1
    int* blockSums  = offsets + N_NODES + 1;           // SCAN_NB
    unsigned short* wp1h = (unsigned short*)(((uintptr_t)(blockSums + SCAN_NB) + 15) & ~(uintptr_t)15);
    unsigned short* wp1l = wp1h + 65536;               // 256*256
    unsigned short* wp2h = wp1l + 65536;
    unsigned short* wp2l = wp2h + 32768;               // 256*128
    float* v1s = vbuf, *v1d = vbuf + HID, *v2s = vbuf + 2 * HID, *v2d = vbuf + 3 * HID;
    float* h2 = h1;

    const int edgeBlocks = (N_EDGES + 255) / 256;
    const int waveBlocksN = (N_NODES + 3) / 4;
    const int gemmBlocks = (N_NODES + 127) / 128;

    // -------- CSR build --------
    hipMemsetAsync(counts, 0, N_NODES * sizeof(int), stream);
    hist_kernel<<<edgeBlocks, 256, 0, stream>>>(dst, counts);
    block_scan_kernel<<<SCAN_NB, 256, 0, stream>>>(counts, offsets, blockSums, N_NODES);
    scan_sums_kernel<<<1, 64, 0, stream>>>(blockSums, SCAN_NB);
    add_offsets_kernel<<<SCAN_NB, 256, 0, stream>>>(offsets, blockSums, N_NODES);
    hipMemsetAsync(counts, 0, N_NODES * sizeof(int), stream);
    scatter_kernel<<<edgeBlocks, 256, 0, stream>>>(src, dst, offsets, counts, src_sorted);

    // -------- W packing --------
    pack_w_kernel<<<32, 256, 0, stream>>>(W1s, wp1h, wp1l, HID);
    pack_w_kernel<<<16, 256, 0, stream>>>(W2s, wp2h, wp2l, OUT_C);

    // -------- layer 1 --------
    compute_v_kernel<<<HID, 64, 0, stream>>>(W1s, att1s, v1s, HID);
    compute_v_kernel<<<HID, 64, 0, stream>>>(W1d, att1d, v1d, HID);
    compute_a_kernel<<<waveBlocksN, 256, 0, stream>>>(x, v1s, v1d, a_s, a_d, N_NODES, HID);
    mfma_gemm_kernel<HID><<<dim3(gemmBlocks, 2), 256, 0, stream>>>(x, wp1h, wp1l, h1, N_NODES);
    fused_aggregate_kernel<HID, true><<<waveBlocksN, 256, 0, stream>>>(
        offsets, src_sorted, a_s, a_d, h1, b1, act2);

    // -------- layer 2 --------
    compute_v_kernel<<<HID, 64, 0, stream>>>(W2s, att2s, v2s, OUT_C);
    compute_v_kernel<<<HID, 64, 0, stream>>>(W2d, att2d, v2d, OUT_C);
    compute_a_kernel<<<waveBlocksN, 256, 0, stream>>>(act2, v2s, v2d, a_s, a_d, N_NODES, HID);
    mfma_gemm_kernel<OUT_C><<<dim3(gemmBlocks, 1), 256, 0, stream>>>(act2, wp2h, wp2l, h2, N_NODES);
    fused_aggregate_kernel<OUT_C, false><<<waveBlocksN, 256, 0, stream>>>(
        offsets, src_sorted, a_s, a_d, h2, b2, out);
}